// Round 6
// baseline (431.876 us; speedup 1.0000x reference)
//
#include <hip/hip_runtime.h>

#define C_IN   8
#define CH     8
#define Hh     128
#define Ww     192
#define HW     (Hh*Ww)
#define NINST  128
#define NPAR   169
#define OH     256
#define OW     384
#define B      4             // owned source rows per block
#define RT     (B+1)         // computed rows (incl. bottom halo)
#define NRG    (Hh/B)        // 32 row groups

typedef float f32x2 __attribute__((ext_vector_type(2)));
typedef float f32x4 __attribute__((ext_vector_type(4)));

// Packed LDS weight layout (16B-aligned, 192 floats):
//   [0,96):   w0 as [8][12] (10 used + 2 pad)
//   [96,160): w1 as [8][8]
//   [160,168): w2[8]
//   [168,176): b0[8]  [176,184): b1[8]  [184]: b2
//
// Output mapping (verified R3-R5): block with source rows [r0, r0+B] writes
// out rows [2r0+2, 2r0+2+2B); rg==0 adds rows {0,1}; rg==NRG-1 clips at 256.

// Compute KB rows of logits (source rows min(r0+i0+k,127)) into sl.
template <int KB>
__device__ __forceinline__ void do_rows(int r0, int i0, const float* __restrict__ fb,
                                        const float* __restrict__ W,
                                        float rx, float iyv, float inv_soi,
                                        int x, float (*__restrict__ sl)[Ww])
{
    float f[KB][C_IN];
    float ry[KB];
    #pragma unroll
    for (int k = 0; k < KB; ++k) {
        const int sr = min(r0 + i0 + k, Hh - 1);
        ry[k] = (iyv - (float)(sr * 8 + 4)) * inv_soi;
        #pragma unroll
        for (int c = 0; c < C_IN; ++c)
            f[k][c] = fb[c * HW + sr * Ww];
    }

    float h1[KB][CH];
    #pragma unroll
    for (int o = 0; o < CH; ++o) {
        const f32x4 wa = *(const f32x4*)(W + o * 12 + 0);
        const f32x4 wb = *(const f32x4*)(W + o * 12 + 4);
        const f32x4 wc = *(const f32x4*)(W + o * 12 + 8);   // .z/.w pad
        const float bo = W[168 + o];
        #pragma unroll
        for (int k = 0; k < KB; ++k) {
            float a = fmaf(wa.x, rx, fmaf(wa.y, ry[k], bo));
            a = fmaf(wa.z, f[k][0], a);
            a = fmaf(wa.w, f[k][1], a);
            a = fmaf(wb.x, f[k][2], a);
            a = fmaf(wb.y, f[k][3], a);
            a = fmaf(wb.z, f[k][4], a);
            a = fmaf(wb.w, f[k][5], a);
            a = fmaf(wc.x, f[k][6], a);
            a = fmaf(wc.y, f[k][7], a);
            h1[k][o] = fmaxf(a, 0.0f);
        }
    }

    float h2[KB][CH];
    #pragma unroll
    for (int o = 0; o < CH; ++o) {
        const f32x4 wa = *(const f32x4*)(W + 96 + o * 8 + 0);
        const f32x4 wb = *(const f32x4*)(W + 96 + o * 8 + 4);
        const float bo = W[176 + o];
        #pragma unroll
        for (int k = 0; k < KB; ++k) {
            float a = bo;
            a = fmaf(wa.x, h1[k][0], a);
            a = fmaf(wa.y, h1[k][1], a);
            a = fmaf(wa.z, h1[k][2], a);
            a = fmaf(wa.w, h1[k][3], a);
            a = fmaf(wb.x, h1[k][4], a);
            a = fmaf(wb.y, h1[k][5], a);
            a = fmaf(wb.z, h1[k][6], a);
            a = fmaf(wb.w, h1[k][7], a);
            h2[k][o] = fmaxf(a, 0.0f);
        }
    }

    const f32x4 wa = *(const f32x4*)(W + 160);
    const f32x4 wb = *(const f32x4*)(W + 164);
    const float bo = W[184];
    #pragma unroll
    for (int k = 0; k < KB; ++k) {
        float z = bo;
        z = fmaf(wa.x, h2[k][0], z);
        z = fmaf(wa.y, h2[k][1], z);
        z = fmaf(wa.z, h2[k][2], z);
        z = fmaf(wa.w, h2[k][3], z);
        z = fmaf(wb.x, h2[k][4], z);
        z = fmaf(wb.y, h2[k][5], z);
        z = fmaf(wb.z, h2[k][6], z);
        z = fmaf(wb.w, h2[k][7], z);
        sl[i0 + k][x] = z;
    }
}

__global__ __launch_bounds__(192, 8)
void fused_maskhead_kernel(const float* __restrict__ feats,
                           const float* __restrict__ params,
                           const float* __restrict__ locs,
                           const int* __restrict__ im_inds,
                           const int* __restrict__ fpn,
                           float* __restrict__ out)
{
    __shared__ __align__(16) float sw[192];
    __shared__ float sl[RT][Ww];

    const int rg   = blockIdx.x;    // 0..31
    const int inst = blockIdx.y;    // 0..127
    const int x    = threadIdx.x;   // 0..191 — one column per thread
    const int r0   = rg * B;

    // stage + repack params (coalesced global read, remapped LDS write)
    if (x < NPAR) {
        const int r = x;
        int dst;
        if (r < 80)       { const int o = r / 10; dst = o * 12 + (r - o * 10); }
        else if (r < 144) dst = 96  + (r - 80);
        else if (r < 152) dst = 160 + (r - 144);
        else if (r < 160) dst = 168 + (r - 152);
        else if (r < 168) dst = 176 + (r - 160);
        else              dst = 184;
        sw[dst] = params[inst * NPAR + r];
    }

    const float ixv = locs[inst * 2 + 0];
    const float iyv = locs[inst * 2 + 1];
    const float inv_soi = 1.0f / (float)(64 << fpn[inst]);
    const float rx = (ixv - (float)(x * 8 + 4)) * inv_soi;
    const float* fb = feats + (size_t)im_inds[inst] * (C_IN * HW) + x;

    __syncthreads();

    // rows in batches of 2 (+1 tail) to keep live registers <= 64
    #pragma unroll 1
    for (int i0 = 0; i0 < B; i0 += 2)
        do_rows<2>(r0, i0, fb, sw, rx, iyv, inv_soi, x, sl);
    do_rows<1>(r0, B, fb, sw, rx, iyv, inv_soi, x, sl);

    __syncthreads();

    // ---- 2x aligned bilinear from LDS tile
    f32x2* outf2 = (f32x2*)out;
    const int xm1 = max(x - 1, 0);
    const int jlo = (rg == 0) ? -2 : 0;
    const int jhi = (rg == NRG - 1) ? 2 * B - 2 : 2 * B;

    #pragma unroll 4
    for (int jj = jlo; jj < jhi; ++jj) {
        const int oy  = 2 * r0 + 2 + jj;
        const int ay  = max(oy - 1, 0);
        const int y0l = (ay >> 1) - r0;            // 0..B
        const int y1l = min(y0l + 1, B);           // clamp only when fy==0
        const float fy = (ay & 1) ? 0.5f : 0.0f;

        const float t01 = sl[y0l][x];
        const float t00 = sl[y0l][xm1];
        const float t11 = sl[y1l][x];
        const float t10 = sl[y1l][xm1];

        const float rma = fmaf(fy, t10 - t00, t00);
        const float rmb = fmaf(fy, t11 - t01, t01);

        f32x2 v;
        v.x = 0.5f * (rma + rmb);
        v.y = rmb;
        outf2[((size_t)inst * OH + oy) * (OW / 2) + x] = v;
    }
}

extern "C" void kernel_launch(void* const* d_in, const int* in_sizes, int n_in,
                              void* d_out, int out_size, void* d_ws, size_t ws_size,
                              hipStream_t stream) {
    const float* feats  = (const float*)d_in[0];
    const float* params = (const float*)d_in[1];
    const float* locs   = (const float*)d_in[2];
    const int*   im     = (const int*)d_in[3];
    const int*   fpn    = (const int*)d_in[4];
    float* out = (float*)d_out;

    dim3 grid(NRG, NINST);   // 32 x 128 = 4096 blocks
    fused_maskhead_kernel<<<grid, 192, 0, stream>>>(feats, params, locs, im, fpn, out);
}

// Round 7
// 222.471 us; speedup vs baseline: 1.9413x; 1.9413x over previous
//
#include <hip/hip_runtime.h>

#define C_IN   8
#define CH     8
#define Hh     128
#define Ww     192
#define HW     (Hh*Ww)
#define NINST  128
#define NPAR   169
#define OH     256
#define OW     384
#define B      4             // owned source rows per block
#define RT     (B+1)         // computed rows (incl. bottom halo)
#define NRG    (Hh/B)        // 32 row groups

typedef float f32x2 __attribute__((ext_vector_type(2)));
typedef float f32x4 __attribute__((ext_vector_type(4)));

// Packed LDS weight layout (16B-aligned, 192 floats):
//   [0,96):   w0 as [8][12] (10 used + 2 pad)
//   [96,160): w1 as [8][8]
//   [160,168): w2[8]
//   [168,176): b0[8]  [176,184): b1[8]  [184]: b2
//
// Output mapping (verified R3-R6): block with source rows [r0, r0+B] writes
// out rows [2r0+2, 2r0+2+2B); rg==0 adds rows {0,1}; rg==NRG-1 clips at 256.

// Compute KB rows of logits (source rows min(r0+i0+k,127)) into sl.
template <int KB>
__device__ __forceinline__ void do_rows(int r0, int i0, const float* __restrict__ fb,
                                        const float* __restrict__ W,
                                        float rx, float iyv, float inv_soi,
                                        int x, float (*__restrict__ sl)[Ww])
{
    float f[KB][C_IN];
    float ry[KB];
    #pragma unroll
    for (int k = 0; k < KB; ++k) {
        const int sr = min(r0 + i0 + k, Hh - 1);
        ry[k] = (iyv - (float)(sr * 8 + 4)) * inv_soi;
        #pragma unroll
        for (int c = 0; c < C_IN; ++c)
            f[k][c] = fb[c * HW + sr * Ww];
    }

    float h1[KB][CH];
    #pragma unroll
    for (int o = 0; o < CH; ++o) {
        const f32x4 wa = *(const f32x4*)(W + o * 12 + 0);
        const f32x4 wb = *(const f32x4*)(W + o * 12 + 4);
        const f32x4 wc = *(const f32x4*)(W + o * 12 + 8);   // .z/.w pad
        const float bo = W[168 + o];
        #pragma unroll
        for (int k = 0; k < KB; ++k) {
            float a = fmaf(wa.x, rx, fmaf(wa.y, ry[k], bo));
            a = fmaf(wa.z, f[k][0], a);
            a = fmaf(wa.w, f[k][1], a);
            a = fmaf(wb.x, f[k][2], a);
            a = fmaf(wb.y, f[k][3], a);
            a = fmaf(wb.z, f[k][4], a);
            a = fmaf(wb.w, f[k][5], a);
            a = fmaf(wc.x, f[k][6], a);
            a = fmaf(wc.y, f[k][7], a);
            h1[k][o] = fmaxf(a, 0.0f);
        }
    }

    float h2[KB][CH];
    #pragma unroll
    for (int o = 0; o < CH; ++o) {
        const f32x4 wa = *(const f32x4*)(W + 96 + o * 8 + 0);
        const f32x4 wb = *(const f32x4*)(W + 96 + o * 8 + 4);
        const float bo = W[176 + o];
        #pragma unroll
        for (int k = 0; k < KB; ++k) {
            float a = bo;
            a = fmaf(wa.x, h1[k][0], a);
            a = fmaf(wa.y, h1[k][1], a);
            a = fmaf(wa.z, h1[k][2], a);
            a = fmaf(wa.w, h1[k][3], a);
            a = fmaf(wb.x, h1[k][4], a);
            a = fmaf(wb.y, h1[k][5], a);
            a = fmaf(wb.z, h1[k][6], a);
            a = fmaf(wb.w, h1[k][7], a);
            h2[k][o] = fmaxf(a, 0.0f);
        }
    }

    const f32x4 wa = *(const f32x4*)(W + 160);
    const f32x4 wb = *(const f32x4*)(W + 164);
    const float bo = W[184];
    #pragma unroll
    for (int k = 0; k < KB; ++k) {
        float z = bo;
        z = fmaf(wa.x, h2[k][0], z);
        z = fmaf(wa.y, h2[k][1], z);
        z = fmaf(wa.z, h2[k][2], z);
        z = fmaf(wa.w, h2[k][3], z);
        z = fmaf(wb.x, h2[k][4], z);
        z = fmaf(wb.y, h2[k][5], z);
        z = fmaf(wb.z, h2[k][6], z);
        z = fmaf(wb.w, h2[k][7], z);
        sl[i0 + k][x] = z;
    }
}

__global__ __launch_bounds__(192, 4)
void fused_maskhead_kernel(const float* __restrict__ feats,
                           const float* __restrict__ params,
                           const float* __restrict__ locs,
                           const int* __restrict__ im_inds,
                           const int* __restrict__ fpn,
                           float* __restrict__ out)
{
    __shared__ __align__(16) float sw[192];
    __shared__ float sl[RT][Ww];

    const int rg   = blockIdx.x;    // 0..31
    const int inst = blockIdx.y;    // 0..127
    const int x    = threadIdx.x;   // 0..191 — one column per thread
    const int r0   = rg * B;

    // stage + repack params (coalesced global read, remapped LDS write)
    if (x < NPAR) {
        const int r = x;
        int dst;
        if (r < 80)       { const int o = r / 10; dst = o * 12 + (r - o * 10); }
        else if (r < 144) dst = 96  + (r - 80);
        else if (r < 152) dst = 160 + (r - 144);
        else if (r < 160) dst = 168 + (r - 152);
        else if (r < 168) dst = 176 + (r - 160);
        else              dst = 184;
        sw[dst] = params[inst * NPAR + r];
    }

    const float ixv = locs[inst * 2 + 0];
    const float iyv = locs[inst * 2 + 1];
    const float inv_soi = 1.0f / (float)(64 << fpn[inst]);
    const float rx = (ixv - (float)(x * 8 + 4)) * inv_soi;
    const float* fb = feats + (size_t)im_inds[inst] * (C_IN * HW) + x;

    __syncthreads();

    // rows in batches of 2 (+1 tail) to keep live registers modest
    #pragma unroll 1
    for (int i0 = 0; i0 < B; i0 += 2)
        do_rows<2>(r0, i0, fb, sw, rx, iyv, inv_soi, x, sl);
    do_rows<1>(r0, B, fb, sw, rx, iyv, inv_soi, x, sl);

    __syncthreads();

    // ---- 2x aligned bilinear from LDS tile
    f32x2* outf2 = (f32x2*)out;
    const int xm1 = max(x - 1, 0);
    const int jlo = (rg == 0) ? -2 : 0;
    const int jhi = (rg == NRG - 1) ? 2 * B - 2 : 2 * B;

    #pragma unroll 4
    for (int jj = jlo; jj < jhi; ++jj) {
        const int oy  = 2 * r0 + 2 + jj;
        const int ay  = max(oy - 1, 0);
        const int y0l = (ay >> 1) - r0;            // 0..B
        const int y1l = min(y0l + 1, B);           // clamp only when fy==0
        const float fy = (ay & 1) ? 0.5f : 0.0f;

        const float t01 = sl[y0l][x];
        const float t00 = sl[y0l][xm1];
        const float t11 = sl[y1l][x];
        const float t10 = sl[y1l][xm1];

        const float rma = fmaf(fy, t10 - t00, t00);
        const float rmb = fmaf(fy, t11 - t01, t01);

        f32x2 v;
        v.x = 0.5f * (rma + rmb);
        v.y = rmb;
        outf2[((size_t)inst * OH + oy) * (OW / 2) + x] = v;
    }
}

extern "C" void kernel_launch(void* const* d_in, const int* in_sizes, int n_in,
                              void* d_out, int out_size, void* d_ws, size_t ws_size,
                              hipStream_t stream) {
    const float* feats  = (const float*)d_in[0];
    const float* params = (const float*)d_in[1];
    const float* locs   = (const float*)d_in[2];
    const int*   im     = (const int*)d_in[3];
    const int*   fpn    = (const int*)d_in[4];
    float* out = (float*)d_out;

    dim3 grid(NRG, NINST);   // 32 x 128 = 4096 blocks
    fused_maskhead_kernel<<<grid, 192, 0, stream>>>(feats, params, locs, im, fpn, out);
}

// Round 8
// 160.740 us; speedup vs baseline: 2.6868x; 1.3840x over previous
//
#include <hip/hip_runtime.h>

#define C_IN   8
#define CH     8
#define Hh     128
#define Ww     192
#define HW     (Hh*Ww)
#define NINST  128
#define NPAR   169
#define OH     256
#define OW     384
#define B      4             // owned source rows per block
#define RT     (B+1)         // computed rows (incl. bottom halo)
#define NRG    (Hh/B)        // 32 row groups

typedef float f32x2 __attribute__((ext_vector_type(2)));
typedef float f32x4 __attribute__((ext_vector_type(4)));

// Packed LDS weight layout (16B-aligned, 192 floats):
//   [0,96):   w0 as [8][12] (10 used + 2 pad)
//   [96,160): w1 as [8][8]
//   [160,168): w2[8]
//   [168,176): b0[8]  [176,184): b1[8]  [184]: b2
//
// Output mapping (verified R3-R7): block with source rows [r0, r0+B] writes
// out rows [2r0+2, 2r0+2+2B); rg==0 adds rows {0,1}; rg==NRG-1 clips at 256.
//
// __launch_bounds__ NOTE (R6/R7 lesson): second arg w caps VGPRs at ~256/w on
// this toolchain (w=8 -> 32 VGPR, w=4 -> 64 VGPR => spills, 0.5-1.5 GB scratch
// traffic). Natural demand here is ~75 VGPR -> w=3 (cap ~85) is the safe max.

// Compute KB rows of logits (source rows min(r0+i0+k,127)) into sl.
template <int KB>
__device__ __forceinline__ void do_rows(int r0, int i0, const float* __restrict__ fb,
                                        const float* __restrict__ W,
                                        float rx, float iyv, float inv_soi,
                                        int x, float (*__restrict__ sl)[Ww])
{
    float f[KB][C_IN];
    float ry[KB];
    #pragma unroll
    for (int k = 0; k < KB; ++k) {
        const int sr = min(r0 + i0 + k, Hh - 1);
        ry[k] = (iyv - (float)(sr * 8 + 4)) * inv_soi;
        #pragma unroll
        for (int c = 0; c < C_IN; ++c)
            f[k][c] = fb[c * HW + sr * Ww];
    }

    float h1[KB][CH];
    #pragma unroll
    for (int o = 0; o < CH; ++o) {
        const f32x4 wa = *(const f32x4*)(W + o * 12 + 0);
        const f32x4 wb = *(const f32x4*)(W + o * 12 + 4);
        const f32x4 wc = *(const f32x4*)(W + o * 12 + 8);   // .z/.w pad
        const float bo = W[168 + o];
        #pragma unroll
        for (int k = 0; k < KB; ++k) {
            float a = fmaf(wa.x, rx, fmaf(wa.y, ry[k], bo));
            a = fmaf(wa.z, f[k][0], a);
            a = fmaf(wa.w, f[k][1], a);
            a = fmaf(wb.x, f[k][2], a);
            a = fmaf(wb.y, f[k][3], a);
            a = fmaf(wb.z, f[k][4], a);
            a = fmaf(wb.w, f[k][5], a);
            a = fmaf(wc.x, f[k][6], a);
            a = fmaf(wc.y, f[k][7], a);
            h1[k][o] = fmaxf(a, 0.0f);
        }
    }

    float h2[KB][CH];
    #pragma unroll
    for (int o = 0; o < CH; ++o) {
        const f32x4 wa = *(const f32x4*)(W + 96 + o * 8 + 0);
        const f32x4 wb = *(const f32x4*)(W + 96 + o * 8 + 4);
        const float bo = W[176 + o];
        #pragma unroll
        for (int k = 0; k < KB; ++k) {
            float a = bo;
            a = fmaf(wa.x, h1[k][0], a);
            a = fmaf(wa.y, h1[k][1], a);
            a = fmaf(wa.z, h1[k][2], a);
            a = fmaf(wa.w, h1[k][3], a);
            a = fmaf(wb.x, h1[k][4], a);
            a = fmaf(wb.y, h1[k][5], a);
            a = fmaf(wb.z, h1[k][6], a);
            a = fmaf(wb.w, h1[k][7], a);
            h2[k][o] = fmaxf(a, 0.0f);
        }
    }

    const f32x4 wa = *(const f32x4*)(W + 160);
    const f32x4 wb = *(const f32x4*)(W + 164);
    const float bo = W[184];
    #pragma unroll
    for (int k = 0; k < KB; ++k) {
        float z = bo;
        z = fmaf(wa.x, h2[k][0], z);
        z = fmaf(wa.y, h2[k][1], z);
        z = fmaf(wa.z, h2[k][2], z);
        z = fmaf(wa.w, h2[k][3], z);
        z = fmaf(wb.x, h2[k][4], z);
        z = fmaf(wb.y, h2[k][5], z);
        z = fmaf(wb.z, h2[k][6], z);
        z = fmaf(wb.w, h2[k][7], z);
        sl[i0 + k][x] = z;
    }
}

__global__ __launch_bounds__(192, 3)
void fused_maskhead_kernel(const float* __restrict__ feats,
                           const float* __restrict__ params,
                           const float* __restrict__ locs,
                           const int* __restrict__ im_inds,
                           const int* __restrict__ fpn,
                           float* __restrict__ out)
{
    __shared__ __align__(16) float sw[192];
    __shared__ float sl[RT][Ww];

    const int rg   = blockIdx.x;    // 0..31
    const int inst = blockIdx.y;    // 0..127
    const int x    = threadIdx.x;   // 0..191 — one column per thread
    const int r0   = rg * B;

    // stage + repack params (coalesced global read, remapped LDS write)
    if (x < NPAR) {
        const int r = x;
        int dst;
        if (r < 80)       { const int o = r / 10; dst = o * 12 + (r - o * 10); }
        else if (r < 144) dst = 96  + (r - 80);
        else if (r < 152) dst = 160 + (r - 144);
        else if (r < 160) dst = 168 + (r - 152);
        else if (r < 168) dst = 176 + (r - 160);
        else              dst = 184;
        sw[dst] = params[inst * NPAR + r];
    }

    const float ixv = locs[inst * 2 + 0];
    const float iyv = locs[inst * 2 + 1];
    const float inv_soi = 1.0f / (float)(64 << fpn[inst]);
    const float rx = (ixv - (float)(x * 8 + 4)) * inv_soi;
    const float* fb = feats + (size_t)im_inds[inst] * (C_IN * HW) + x;

    __syncthreads();

    // rows in batches of 2 (+1 tail) to keep live registers modest
    #pragma unroll 1
    for (int i0 = 0; i0 < B; i0 += 2)
        do_rows<2>(r0, i0, fb, sw, rx, iyv, inv_soi, x, sl);
    do_rows<1>(r0, B, fb, sw, rx, iyv, inv_soi, x, sl);

    __syncthreads();

    // ---- 2x aligned bilinear from LDS tile
    f32x2* outf2 = (f32x2*)out;
    const int xm1 = max(x - 1, 0);
    const int jlo = (rg == 0) ? -2 : 0;
    const int jhi = (rg == NRG - 1) ? 2 * B - 2 : 2 * B;

    #pragma unroll 4
    for (int jj = jlo; jj < jhi; ++jj) {
        const int oy  = 2 * r0 + 2 + jj;
        const int ay  = max(oy - 1, 0);
        const int y0l = (ay >> 1) - r0;            // 0..B
        const int y1l = min(y0l + 1, B);           // clamp only when fy==0
        const float fy = (ay & 1) ? 0.5f : 0.0f;

        const float t01 = sl[y0l][x];
        const float t00 = sl[y0l][xm1];
        const float t11 = sl[y1l][x];
        const float t10 = sl[y1l][xm1];

        const float rma = fmaf(fy, t10 - t00, t00);
        const float rmb = fmaf(fy, t11 - t01, t01);

        f32x2 v;
        v.x = 0.5f * (rma + rmb);
        v.y = rmb;
        outf2[((size_t)inst * OH + oy) * (OW / 2) + x] = v;
    }
}

extern "C" void kernel_launch(void* const* d_in, const int* in_sizes, int n_in,
                              void* d_out, int out_size, void* d_ws, size_t ws_size,
                              hipStream_t stream) {
    const float* feats  = (const float*)d_in[0];
    const float* params = (const float*)d_in[1];
    const float* locs   = (const float*)d_in[2];
    const int*   im     = (const int*)d_in[3];
    const int*   fpn    = (const int*)d_in[4];
    float* out = (float*)d_out;

    dim3 grid(NRG, NINST);   // 32 x 128 = 4096 blocks
    fused_maskhead_kernel<<<grid, 192, 0, stream>>>(feats, params, locs, im, fpn, out);
}

// Round 9
// 28.340 us; speedup vs baseline: 15.2394x; 5.6720x over previous
//
#include <hip/hip_runtime.h>

#define C_IN   8
#define CH     8
#define Hh     128
#define Ww     192
#define HW     (Hh*Ww)
#define NINST  128
#define NPAR   169
#define OH     256
#define OW     384
#define B      4             // owned source rows per block
#define RT     (B+1)         // computed rows (incl. bottom halo)
#define NRG    (Hh/B)        // 32 row groups

typedef float f32x2 __attribute__((ext_vector_type(2)));
typedef float f32x4 __attribute__((ext_vector_type(4)));

// Packed LDS weight layout (16B-aligned, 192 floats):
//   [0,96):   w0 as [8][12] (10 used + 2 pad)
//   [96,160): w1 as [8][8]
//   [160,168): w2[8]
//   [168,176): b0[8]  [176,184): b1[8]  [184]: b2
//
// Output mapping (verified R3-R8): block with source rows [r0, r0+B] writes
// out rows [2r0+2, 2r0+2+2B); rg==0 adds rows {0,1}; rg==NRG-1 clips at 256.
//
// Codegen lessons: (1) __launch_bounds__ 2nd arg w caps VGPRs ~256/w; w>=4
// spilled (R6/R7: 0.5-1.5 GB scratch traffic). (2) The row-batched do_rows
// restructure spills even at w=3 (R8: WRITE 417MB vs 49MB output). Only this
// monolithic 5-row body is proven spill-free (R5: VGPR 76, WRITE == output).

__global__ __launch_bounds__(192, 3)
void fused_maskhead_kernel(const float* __restrict__ feats,
                           const float* __restrict__ params,
                           const float* __restrict__ locs,
                           const int* __restrict__ im_inds,
                           const int* __restrict__ fpn,
                           float* __restrict__ out)
{
    __shared__ __align__(16) float sw[192];
    __shared__ float sl[RT][Ww];

    const int rg   = blockIdx.x;    // 0..31
    const int inst = blockIdx.y;    // 0..127
    const int x    = threadIdx.x;   // 0..191 — one column per thread
    const int r0   = rg * B;

    // stage + repack params (coalesced global read, remapped LDS write)
    if (x < NPAR) {
        const int r = x;
        int dst;
        if (r < 80)       { const int o = r / 10; dst = o * 12 + (r - o * 10); }
        else if (r < 144) dst = 96  + (r - 80);
        else if (r < 152) dst = 160 + (r - 144);
        else if (r < 160) dst = 168 + (r - 152);
        else if (r < 168) dst = 176 + (r - 160);
        else              dst = 184;
        sw[dst] = params[inst * NPAR + r];
    }

    const float ixv = locs[inst * 2 + 0];
    const float iyv = locs[inst * 2 + 1];
    const float inv_soi = 1.0f / (float)(64 << fpn[inst]);
    const float rx = (ixv - (float)(x * 8 + 4)) * inv_soi;
    const float* fb = feats + (size_t)im_inds[inst] * (C_IN * HW) + x;

    // feats for all RT rows -> 40 regs (issue early, latency hides under LDS wait)
    float f[RT][C_IN];
    float ry[RT];
    #pragma unroll
    for (int k = 0; k < RT; ++k) {
        const int sr = min(r0 + k, Hh - 1);
        ry[k] = (iyv - (float)(sr * 8 + 4)) * inv_soi;
        #pragma unroll
        for (int c = 0; c < C_IN; ++c)
            f[k][c] = fb[c * HW + sr * Ww];
    }

    __syncthreads();

    // ---- layer 1 (10 -> 8), b128 weight reads
    float h1[RT][CH];
    #pragma unroll
    for (int o = 0; o < CH; ++o) {
        const f32x4 wa = *(const f32x4*)(sw + o * 12 + 0);
        const f32x4 wb = *(const f32x4*)(sw + o * 12 + 4);
        const f32x4 wc = *(const f32x4*)(sw + o * 12 + 8);   // .z/.w pad
        const float bo = sw[168 + o];
        #pragma unroll
        for (int k = 0; k < RT; ++k) {
            float a = fmaf(wa.x, rx, fmaf(wa.y, ry[k], bo));
            a = fmaf(wa.z, f[k][0], a);
            a = fmaf(wa.w, f[k][1], a);
            a = fmaf(wb.x, f[k][2], a);
            a = fmaf(wb.y, f[k][3], a);
            a = fmaf(wb.z, f[k][4], a);
            a = fmaf(wb.w, f[k][5], a);
            a = fmaf(wc.x, f[k][6], a);
            a = fmaf(wc.y, f[k][7], a);
            h1[k][o] = fmaxf(a, 0.0f);
        }
    }

    // ---- layer 2 (8 -> 8)
    float h2[RT][CH];
    #pragma unroll
    for (int o = 0; o < CH; ++o) {
        const f32x4 wa = *(const f32x4*)(sw + 96 + o * 8 + 0);
        const f32x4 wb = *(const f32x4*)(sw + 96 + o * 8 + 4);
        const float bo = sw[176 + o];
        #pragma unroll
        for (int k = 0; k < RT; ++k) {
            float a = bo;
            a = fmaf(wa.x, h1[k][0], a);
            a = fmaf(wa.y, h1[k][1], a);
            a = fmaf(wa.z, h1[k][2], a);
            a = fmaf(wa.w, h1[k][3], a);
            a = fmaf(wb.x, h1[k][4], a);
            a = fmaf(wb.y, h1[k][5], a);
            a = fmaf(wb.z, h1[k][6], a);
            a = fmaf(wb.w, h1[k][7], a);
            h2[k][o] = fmaxf(a, 0.0f);
        }
    }

    // ---- layer 3 (8 -> 1) -> LDS logits tile
    {
        const f32x4 wa = *(const f32x4*)(sw + 160);
        const f32x4 wb = *(const f32x4*)(sw + 164);
        const float bo = sw[184];
        #pragma unroll
        for (int k = 0; k < RT; ++k) {
            float z = bo;
            z = fmaf(wa.x, h2[k][0], z);
            z = fmaf(wa.y, h2[k][1], z);
            z = fmaf(wa.z, h2[k][2], z);
            z = fmaf(wa.w, h2[k][3], z);
            z = fmaf(wb.x, h2[k][4], z);
            z = fmaf(wb.y, h2[k][5], z);
            z = fmaf(wb.z, h2[k][6], z);
            z = fmaf(wb.w, h2[k][7], z);
            sl[k][x] = z;
        }
    }

    __syncthreads();

    // ---- 2x aligned bilinear from LDS tile
    f32x2* outf2 = (f32x2*)out;
    const int xm1 = max(x - 1, 0);
    const int jlo = (rg == 0) ? -2 : 0;
    const int jhi = (rg == NRG - 1) ? 2 * B - 2 : 2 * B;

    #pragma unroll 4
    for (int jj = jlo; jj < jhi; ++jj) {
        const int oy  = 2 * r0 + 2 + jj;
        const int ay  = max(oy - 1, 0);
        const int y0l = (ay >> 1) - r0;            // 0..B
        const int y1l = min(y0l + 1, B);           // clamp only when fy==0
        const float fy = (ay & 1) ? 0.5f : 0.0f;

        const float t01 = sl[y0l][x];
        const float t00 = sl[y0l][xm1];
        const float t11 = sl[y1l][x];
        const float t10 = sl[y1l][xm1];

        const float rma = fmaf(fy, t10 - t00, t00);
        const float rmb = fmaf(fy, t11 - t01, t01);

        f32x2 v;
        v.x = 0.5f * (rma + rmb);
        v.y = rmb;
        outf2[((size_t)inst * OH + oy) * (OW / 2) + x] = v;
    }
}

extern "C" void kernel_launch(void* const* d_in, const int* in_sizes, int n_in,
                              void* d_out, int out_size, void* d_ws, size_t ws_size,
                              hipStream_t stream) {
    const float* feats  = (const float*)d_in[0];
    const float* params = (const float*)d_in[1];
    const float* locs   = (const float*)d_in[2];
    const int*   im     = (const int*)d_in[3];
    const int*   fpn    = (const int*)d_in[4];
    float* out = (float*)d_out;

    dim3 grid(NRG, NINST);   // 32 x 128 = 4096 blocks
    fused_maskhead_kernel<<<grid, 192, 0, stream>>>(feats, params, locs, im, fpn, out);
}